// Round 1
// baseline (36.243 us; speedup 1.0000x reference)
//
#include <hip/hip_runtime.h>

__global__ __launch_bounds__(256) void ham3body_kernel(
    const float* __restrict__ y,
    const float* __restrict__ M,
    float* __restrict__ out,
    int B)
{
    int i = blockIdx.x * blockDim.x + threadIdx.x;
    if (i >= B) return;

    const float4* yv = reinterpret_cast<const float4*>(y + (size_t)i * 12);
    float4 v0 = yv[0];
    float4 v1 = yv[1];
    float4 v2 = yv[2];

    // Row layout: x1 y1 x2 y2 | x3 y3 p1x p1y | p2x p2y p3x p3y
    float x1 = v0.x, y1 = v0.y, x2 = v0.z, y2 = v0.w;
    float x3 = v1.x, y3 = v1.y;
    float p1x = v1.z, p1y = v1.w;
    float p2x = v2.x, p2y = v2.y, p3x = v2.z, p3y = v2.w;

    float M0 = M[0], M1 = M[1], M2 = M[2];

    float dx12 = x1 - x2, dy12 = y1 - y2;
    float dx13 = x1 - x3, dy13 = y1 - y3;
    float dx23 = x2 - x3, dy23 = y2 - y3;

    float s12 = dx12 * dx12 + dy12 * dy12;
    float s13 = dx13 * dx13 + dy13 * dy13;
    float s23 = dx23 * dx23 + dy23 * dy23;

    // G = 1; a = M0*M1 / r12^3 = M0*M1 / (s12 * sqrt(s12))
    float a = (M0 * M1) / (s12 * sqrtf(s12));
    float b = (M0 * M2) / (s13 * sqrtf(s13));
    float c = (M1 * M2) / (s23 * sqrtf(s23));

    float4 o0, o1, o2;
    // dq = p / m
    o0.x = p1x / M0;
    o0.y = p1y / M0;
    o0.z = p2x / M1;
    o0.w = p2y / M1;
    o1.x = p3x / M2;
    o1.y = p3y / M2;
    // dp
    o1.z = -(a + b) * x1 + a * x2 + b * x3;
    o1.w = -(a + b) * y1 + a * y2 + b * y3;
    o2.x = a * x1 - (a + c) * x2 + c * x3;
    o2.y = a * y1 - (a + c) * y2 + c * y3;
    o2.z = b * x1 + c * x2 - (b + c) * x3;
    o2.w = b * y1 + c * y2 - (b + c) * y3;

    float4* ov = reinterpret_cast<float4*>(out + (size_t)i * 12);
    ov[0] = o0;
    ov[1] = o1;
    ov[2] = o2;
}

extern "C" void kernel_launch(void* const* d_in, const int* in_sizes, int n_in,
                              void* d_out, int out_size, void* d_ws, size_t ws_size,
                              hipStream_t stream) {
    const float* y = (const float*)d_in[0];
    const float* M = (const float*)d_in[1];
    float* out = (float*)d_out;

    int B = in_sizes[0] / 12;
    int block = 256;
    int grid = (B + block - 1) / block;
    ham3body_kernel<<<grid, block, 0, stream>>>(y, M, out, B);
}

// Round 2
// 33.837 us; speedup vs baseline: 1.0711x; 1.0711x over previous
//
#include <hip/hip_runtime.h>

__global__ __launch_bounds__(256) void ham3body_kernel(
    const float4* __restrict__ y4,
    const float* __restrict__ M,
    float4* __restrict__ o4,
    int B)
{
    __shared__ float4 lds[768];   // 256 rows x 3 float4 = 12 KB

    const int t = threadIdx.x;
    const long nf4 = (long)B * 3;
    const long base = (long)blockIdx.x * 768;

    // ---- stage in: 3 fully-coalesced float4 loads per thread ----
#pragma unroll
    for (int k = 0; k < 3; ++k) {
        long idx = base + k * 256 + t;
        if (idx < nf4) lds[k * 256 + t] = y4[idx];
    }

    const float M0 = M[0], M1 = M[1], M2 = M[2];
    const float invM0 = 1.0f / M0, invM1 = 1.0f / M1, invM2 = 1.0f / M2;

    __syncthreads();

    // ---- per-row compute from LDS (stride-3 f4: conflict-free bank pattern) ----
    float4 v0 = lds[t * 3 + 0];
    float4 v1 = lds[t * 3 + 1];
    float4 v2 = lds[t * 3 + 2];

    // Row layout: x1 y1 x2 y2 | x3 y3 p1x p1y | p2x p2y p3x p3y
    float x1 = v0.x, y1 = v0.y, x2 = v0.z, y2 = v0.w;
    float x3 = v1.x, y3 = v1.y;
    float p1x = v1.z, p1y = v1.w;
    float p2x = v2.x, p2y = v2.y, p3x = v2.z, p3y = v2.w;

    float dx12 = x1 - x2, dy12 = y1 - y2;
    float dx13 = x1 - x3, dy13 = y1 - y3;
    float dx23 = x2 - x3, dy23 = y2 - y3;

    float s12 = dx12 * dx12 + dy12 * dy12;
    float s13 = dx13 * dx13 + dy13 * dy13;
    float s23 = dx23 * dx23 + dy23 * dy23;

    // 1/r^3 = rsq(s)^3  (G = 1)
    float i12 = __builtin_amdgcn_rsqf(s12);
    float i13 = __builtin_amdgcn_rsqf(s13);
    float i23 = __builtin_amdgcn_rsqf(s23);
    float a = (M0 * M1) * (i12 * i12 * i12);
    float b = (M0 * M2) * (i13 * i13 * i13);
    float c = (M1 * M2) * (i23 * i23 * i23);

    float4 o0, o1, o2;
    o0.x = p1x * invM0;
    o0.y = p1y * invM0;
    o0.z = p2x * invM1;
    o0.w = p2y * invM1;
    o1.x = p3x * invM2;
    o1.y = p3y * invM2;
    o1.z = -(a + b) * x1 + a * x2 + b * x3;
    o1.w = -(a + b) * y1 + a * y2 + b * y3;
    o2.x = a * x1 - (a + c) * x2 + c * x3;
    o2.y = a * y1 - (a + c) * y2 + c * y3;
    o2.z = b * x1 + c * x2 - (b + c) * x3;
    o2.w = b * y1 + c * y2 - (b + c) * y3;

    __syncthreads();   // all LDS reads done before overwrite

    lds[t * 3 + 0] = o0;
    lds[t * 3 + 1] = o1;
    lds[t * 3 + 2] = o2;

    __syncthreads();

    // ---- stage out: 3 fully-coalesced float4 stores per thread ----
#pragma unroll
    for (int k = 0; k < 3; ++k) {
        long idx = base + k * 256 + t;
        if (idx < nf4) o4[idx] = lds[k * 256 + t];
    }
}

extern "C" void kernel_launch(void* const* d_in, const int* in_sizes, int n_in,
                              void* d_out, int out_size, void* d_ws, size_t ws_size,
                              hipStream_t stream) {
    const float4* y = (const float4*)d_in[0];
    const float* M = (const float*)d_in[1];
    float4* out = (float4*)d_out;

    int B = in_sizes[0] / 12;
    int block = 256;
    int grid = (B + block - 1) / block;
    ham3body_kernel<<<grid, block, 0, stream>>>(y, M, out, B);
}